// Round 22
// baseline (238.222 us; speedup 1.0000x reference)
//
#include <hip/hip_runtime.h>
#include <hip/hip_fp16.h>
#include <math.h>

#define N_NODES 100000
#define N_EDGES 1600000
#define IN_FEATS 128
#define H_FEATS 64
#define NBUK 500          // buckets
#define BSZ 200           // nodes per bucket (500*200 = 100000)
#define NBA 512           // blocks for count/scatter
#define ACHUNK 3125       // 512*3125 = 1600000 exactly

typedef _Float16 f16x8 __attribute__((ext_vector_type(8)));
typedef float f32x4 __attribute__((ext_vector_type(4)));

// ---------------- A: per-block bucket histogram (LDS atomics only) ----------------
__global__ __launch_bounds__(256) void bucketA_kernel(const int* __restrict__ dst,
                                                      int* __restrict__ blkcnt) {
    __shared__ int cnt[NBUK];
    int t = threadIdx.x;
    for (int i = t; i < NBUK; i += 256) cnt[i] = 0;
    __syncthreads();
    int e0 = blockIdx.x * ACHUNK;
    for (int e = e0 + t; e < e0 + ACHUNK; e += 256)
        atomicAdd(&cnt[dst[e] / BSZ], 1);
    __syncthreads();
    for (int i = t; i < NBUK; i += 256)
        blkcnt[blockIdx.x * NBUK + i] = cnt[i];   // coalesced
}

// ---------------- B1: per-bucket exclusive scan over blocks + totals ----------------
__global__ __launch_bounds__(512) void bucketB1_kernel(const int* __restrict__ blkcnt,
                                                       int* __restrict__ boff,
                                                       int* __restrict__ buktot) {
    __shared__ int tmp[512];
    int b = blockIdx.x;      // bucket
    int t = threadIdx.x;     // block index
    int v = blkcnt[t * NBUK + b];
    tmp[t] = v;
    __syncthreads();
    #pragma unroll
    for (int off = 1; off < 512; off <<= 1) {
        int x = (t >= off) ? tmp[t - off] : 0;
        __syncthreads();
        tmp[t] += x;
        __syncthreads();
    }
    boff[t * NBUK + b] = tmp[t] - v;
    if (t == 511) buktot[b] = tmp[511];
}

// ---------------- B2: exclusive scan of bucket totals ----------------
__global__ __launch_bounds__(512) void bucketB2_kernel(const int* __restrict__ buktot,
                                                       int* __restrict__ bukbase,
                                                       int* __restrict__ rowp) {
    __shared__ int tmp[512];
    int t = threadIdx.x;
    int v = (t < NBUK) ? buktot[t] : 0;
    tmp[t] = v;
    __syncthreads();
    #pragma unroll
    for (int off = 1; off < 512; off <<= 1) {
        int x = (t >= off) ? tmp[t - off] : 0;
        __syncthreads();
        tmp[t] += x;
        __syncthreads();
    }
    if (t < NBUK) bukbase[t] = tmp[t] - v;
    if (t == 0) rowp[N_NODES] = N_EDGES;
}

// ---------------- C: scatter packed edges into bucket-sorted ebuck ----------------
// pack = (src << 8) | (dst % BSZ): src < 2^17, local dst < 2^8 -> 25 bits.
__global__ __launch_bounds__(256) void bucketC_kernel(const int* __restrict__ src,
                                                      const int* __restrict__ dst,
                                                      const int* __restrict__ boff,
                                                      const int* __restrict__ bukbase,
                                                      int* __restrict__ ebuck) {
    __shared__ int sbase[NBUK];
    __shared__ int cur[NBUK];
    int t = threadIdx.x;
    for (int i = t; i < NBUK; i += 256) {
        sbase[i] = bukbase[i] + boff[blockIdx.x * NBUK + i];
        cur[i] = 0;
    }
    __syncthreads();
    int e0 = blockIdx.x * ACHUNK;
    for (int e = e0 + t; e < e0 + ACHUNK; e += 256) {
        int d = dst[e];
        int b = d / BSZ;
        int r = atomicAdd(&cur[b], 1);
        ebuck[sbase[b] + r] = (src[e] << 8) | (d - b * BSZ);
    }
}

// ---------------- D (fused): per-bucket degrees->rowp/dinv + rank -> esrc ----------
// Entirely bucket-local (no global dinv needed since esrc carries src only);
// rowp bases kept in LDS between the two sub-phases.
__global__ __launch_bounds__(256) void bucketD_kernel(const int* __restrict__ ebuck,
                                                      const int* __restrict__ bukbase,
                                                      const int* __restrict__ buktot,
                                                      int* __restrict__ rowp,
                                                      float* __restrict__ dinv,
                                                      int* __restrict__ esrc) {
    __shared__ int deg[BSZ];
    __shared__ int tmp[256];
    __shared__ int rp[BSZ];
    __shared__ int cur2[BSZ];
    int t = threadIdx.x;
    int buk = blockIdx.x;
    int nlo = buk * BSZ;
    int base = bukbase[buk];
    int cnt = buktot[buk];
    for (int i = t; i < BSZ; i += 256) { deg[i] = 0; cur2[i] = 0; }
    __syncthreads();
    for (int k = t; k < cnt; k += 256)
        atomicAdd(&deg[ebuck[base + k] & 255], 1);
    __syncthreads();
    int v = (t < BSZ) ? deg[t] : 0;
    tmp[t] = v;
    __syncthreads();
    #pragma unroll
    for (int off = 1; off < 256; off <<= 1) {
        int x = (t >= off) ? tmp[t - off] : 0;
        __syncthreads();
        tmp[t] += x;
        __syncthreads();
    }
    if (t < BSZ) {
        int rbase = base + tmp[t] - v;
        rp[t] = rbase;
        rowp[nlo + t] = rbase;
        dinv[nlo + t] = rsqrtf(fmaxf((float)v, 1.0f));
    }
    __syncthreads();
    for (int k = t; k < cnt; k += 256) {
        int p = ebuck[base + k];
        int ld = p & 255;
        int r = atomicAdd(&cur2[ld], 1);
        esrc[rp[ld] + r] = p >> 8;
    }
}

// ---------------- prep: pack Weff/W1/W2 into fp16 MFMA B-fragment order ----------------
// Fragment (s,nt): lane l, elem j holds B[k = 32s + (l>>4)*8 + j][n = nt*16 + (l&15)]
__global__ __launch_bounds__(256) void prep_kernel(const float* __restrict__ thetas,
                                                   const float* __restrict__ Wm1,
                                                   const float* __restrict__ W1,
                                                   const float* __restrict__ W2,
                                                   __half* __restrict__ Bpack,
                                                   __half* __restrict__ W1p,
                                                   __half* __restrict__ W2p) {
    int u = blockIdx.x * 256 + threadIdx.x;
    if (u < 16384) {
        int j = u & 7, lane = (u >> 3) & 63, frag = u >> 9;
        int nt = frag & 3, s = frag >> 2;
        int k = 32 * s + ((lane >> 4) << 3) + j;
        int q = k >> 6, f = k & 63;
        int n = nt * 16 + (lane & 15);
        float acc = 0.f;
        #pragma unroll
        for (int c = 0; c < 3; ++c)
            acc = fmaf(thetas[c * 4 + q], Wm1[(c * 64 + f) * 64 + n], acc);
        Bpack[u] = __float2half(acc);
    } else if (u < 16384 + 8192) {
        int v = u - 16384;
        int j = v & 7, lane = (v >> 3) & 63, frag = v >> 9;   // frag 0..15
        int nt = frag & 3, s = frag >> 2;
        int k = 32 * s + ((lane >> 4) << 3) + j;              // 0..127
        int n = nt * 16 + (lane & 15);
        W1p[v] = __float2half(W1[k * 64 + n]);
    } else if (u < 16384 + 8192 + 4096) {
        int v = u - 24576;
        int j = v & 7, lane = (v >> 3) & 63, frag = v >> 9;   // frag 0..7
        int nt = frag & 3, s2 = frag >> 2;
        int k = 32 * s2 + ((lane >> 4) << 3) + j;             // 0..63
        int n = nt * 16 + (lane & 15);
        W2p[v] = __float2half(W2[k * 64 + n]);
    }
}

// ---------------- trunk (MFMA): H = fp16(relu(relu(X@W1+b1)@W2+b2)) ----------------
// ONE 16-row tile per wave. Layouts identical to final_mfma (verified).
// Swizzle: byte ^= (row&7)<<4.
__global__ __launch_bounds__(256) void trunk_mfma_kernel(
    const float* __restrict__ X, const __half* __restrict__ W1p, const float* __restrict__ b1,
    const __half* __restrict__ W2p, const float* __restrict__ b2, __half* __restrict__ H)
{
    __shared__ __half hl[4][1024];   // 2 KB per wave
    int t = threadIdx.x;
    int wv = t >> 6, lane = t & 63;
    int r_lo = lane & 15;            // A-frag row / D col
    int g = lane >> 4;               // k-group / D row group
    char* myl = (char*)hl[wv];

    int tile = blockIdx.x * 4 + wv;
    if (tile >= 6250) return;        // 6250*16 = 100000 exactly; no barriers below

    const f16x8* w1f = (const f16x8*)W1p;
    const f16x8* w2f = (const f16x8*)W2p;
    f16x8 w1b[16], w2b[8];
    #pragma unroll
    for (int f = 0; f < 16; ++f) w1b[f] = w1f[f * 64 + lane];
    #pragma unroll
    for (int f = 0; f < 8; ++f)  w2b[f] = w2f[f * 64 + lane];
    float b1v[4], b2v[4];
    #pragma unroll
    for (int nt = 0; nt < 4; ++nt) {
        b1v[nt] = b1[nt * 16 + r_lo];
        b2v[nt] = b2[nt * 16 + r_lo];
    }

    int row0 = tile * 16;
    const float* xb = X + (size_t)(row0 + r_lo) * IN_FEATS + g * 8;
    f16x8 a1[4];
    #pragma unroll
    for (int s = 0; s < 4; ++s) {
        float4 f0 = *(const float4*)(xb + 32 * s);
        float4 f1 = *(const float4*)(xb + 32 * s + 4);
        f16x8 a;
        a[0] = (_Float16)f0.x; a[1] = (_Float16)f0.y;
        a[2] = (_Float16)f0.z; a[3] = (_Float16)f0.w;
        a[4] = (_Float16)f1.x; a[5] = (_Float16)f1.y;
        a[6] = (_Float16)f1.z; a[7] = (_Float16)f1.w;
        a1[s] = a;
    }
    f32x4 acc1[4];
    #pragma unroll
    for (int nt = 0; nt < 4; ++nt) acc1[nt] = (f32x4){0.f, 0.f, 0.f, 0.f};
    #pragma unroll
    for (int s = 0; s < 4; ++s)
        #pragma unroll
        for (int nt = 0; nt < 4; ++nt)
            acc1[nt] = __builtin_amdgcn_mfma_f32_16x16x32_f16(a1[s], w1b[s * 4 + nt], acc1[nt], 0, 0, 0);
    #pragma unroll
    for (int nt = 0; nt < 4; ++nt)
        #pragma unroll
        for (int reg = 0; reg < 4; ++reg) {
            int r = g * 4 + reg;
            int c = nt * 16 + r_lo;
            int byte = (r * 128 + c * 2) ^ ((r & 7) << 4);
            *(__half*)(myl + byte) = __float2half(fmaxf(acc1[nt][reg] + b1v[nt], 0.f));
        }
    f16x8 a2[2];
    #pragma unroll
    for (int s2 = 0; s2 < 2; ++s2) {
        int byte = (r_lo * 128 + 64 * s2 + g * 16) ^ ((r_lo & 7) << 4);
        a2[s2] = *(const f16x8*)(myl + byte);
    }
    f32x4 acc2[4];
    #pragma unroll
    for (int nt = 0; nt < 4; ++nt) acc2[nt] = (f32x4){0.f, 0.f, 0.f, 0.f};
    #pragma unroll
    for (int s2 = 0; s2 < 2; ++s2)
        #pragma unroll
        for (int nt = 0; nt < 4; ++nt)
            acc2[nt] = __builtin_amdgcn_mfma_f32_16x16x32_f16(a2[s2], w2b[s2 * 4 + nt], acc2[nt], 0, 0, 0);
    #pragma unroll
    for (int nt = 0; nt < 4; ++nt)
        #pragma unroll
        for (int reg = 0; reg < 4; ++reg) {
            int r = g * 4 + reg;
            int c = nt * 16 + r_lo;
            int byte = (r * 128 + c * 2) ^ ((r & 7) << 4);
            *(__half*)(myl + byte) = __float2half(fmaxf(acc2[nt][reg] + b2v[nt], 0.f));
        }
    #pragma unroll
    for (int h2 = 0; h2 < 2; ++h2) {
        int R = (lane >> 3) + 8 * h2;    // row 0..15
        int w = lane & 7;                // 16B slot
        int byte = (R * 128 + 16 * (w ^ (R & 7)));
        f16x8 hv = *(const f16x8*)(myl + byte);
        *(f16x8*)(H + (size_t)(row0 + R) * 64 + w * 8) = hv;
    }
}

// ---------------- gather pass: Fnew[n] = Fprev[n] - dinv[n]*sum_e dinv[s_e]*Fprev[s_e]
// esrc stream (4B/edge, sequential); dinv[s] via wave-uniform s_load (400KB,
// L2-resident); 16 independent chains per ladder block. fp32 accumulate.
__global__ __launch_bounds__(256) void gather_kernel(
    const __half* __restrict__ Fprev, const int* __restrict__ rowp,
    const int* __restrict__ esrc, const float* __restrict__ dinv,
    __half* __restrict__ Fnew)
{
    int wv = __builtin_amdgcn_readfirstlane(threadIdx.x >> 6);
    int wid = blockIdx.x * 4 + wv;   // node id (uniform)
    int lane = threadIdx.x & 63;
    int beg = rowp[wid], end = rowp[wid + 1];
    float acc = 0.0f;
    int j = beg;
    for (; j + 15 < end; j += 16) {
        int s[16];
        #pragma unroll
        for (int q = 0; q < 16; ++q) s[q] = esrc[j + q];
        float w[16];
        #pragma unroll
        for (int q = 0; q < 16; ++q) w[q] = dinv[s[q]];
        float v[16];
        #pragma unroll
        for (int q = 0; q < 16; ++q)
            v[q] = __half2float(Fprev[(size_t)s[q] * 64 + lane]);
        #pragma unroll
        for (int q = 0; q < 16; ++q)
            acc = fmaf(v[q], w[q], acc);
    }
    for (; j + 7 < end; j += 8) {
        int s[8];
        #pragma unroll
        for (int q = 0; q < 8; ++q) s[q] = esrc[j + q];
        float w[8];
        #pragma unroll
        for (int q = 0; q < 8; ++q) w[q] = dinv[s[q]];
        float v[8];
        #pragma unroll
        for (int q = 0; q < 8; ++q)
            v[q] = __half2float(Fprev[(size_t)s[q] * 64 + lane]);
        #pragma unroll
        for (int q = 0; q < 8; ++q)
            acc = fmaf(v[q], w[q], acc);
    }
    for (; j + 3 < end; j += 4) {
        int s[4];
        #pragma unroll
        for (int q = 0; q < 4; ++q) s[q] = esrc[j + q];
        float w[4];
        #pragma unroll
        for (int q = 0; q < 4; ++q) w[q] = dinv[s[q]];
        float v[4];
        #pragma unroll
        for (int q = 0; q < 4; ++q)
            v[q] = __half2float(Fprev[(size_t)s[q] * 64 + lane]);
        #pragma unroll
        for (int q = 0; q < 4; ++q)
            acc = fmaf(v[q], w[q], acc);
    }
    for (; j < end; ++j) {
        int s = esrc[j];
        acc = fmaf(__half2float(Fprev[(size_t)s * 64 + lane]), dinv[s], acc);
    }
    float self = __half2float(Fprev[(size_t)wid * 64 + lane]);
    Fnew[(size_t)wid * 64 + lane] = __float2half(self - acc * dinv[wid]);
}

// ---------------- final (MFMA): out = relu(A@B + bm1) @ Wm2 + bm2 ----------------
// ONE 16-row tile per wave. A = [L0|L1|L2|L3] fp16 contiguous; B pre-packed
// fragment order. D: col n = nt*16 + (l&15), row = (l>>4)*4 + reg.
__global__ __launch_bounds__(256) void final_mfma_kernel(
    const __half* __restrict__ L0h, const __half* __restrict__ Bpack,
    const float* __restrict__ Wm2, const float* __restrict__ bm1,
    const float* __restrict__ bm2, float* __restrict__ out)
{
    const size_t NH = (size_t)N_NODES * 64;
    int t = threadIdx.x;
    int wv = t >> 6;
    int lane = t & 63;
    int tile = blockIdx.x * 4 + wv;
    if (tile >= 6250) return;          // 6250 * 16 = 100000 exactly

    const f16x8* bp = (const f16x8*)Bpack;
    f16x8 b[4][8];
    #pragma unroll
    for (int s = 0; s < 8; ++s)
        #pragma unroll
        for (int nt = 0; nt < 4; ++nt)
            b[nt][s] = bp[(s * 4 + nt) * 64 + lane];

    float bm1v[4], w20[4], w21[4];
    #pragma unroll
    for (int nt = 0; nt < 4; ++nt) {
        int n = nt * 16 + (lane & 15);
        bm1v[nt] = bm1[n];
        w20[nt] = Wm2[n * 2 + 0];
        w21[nt] = Wm2[n * 2 + 1];
    }
    float bm20 = bm2[0], bm21 = bm2[1];

    int row0 = tile * 16;
    const __half* abase = L0h + (size_t)(row0 + (lane & 15)) * 64 + ((lane >> 4) << 3);
    f16x8 a[8];
    #pragma unroll
    for (int s = 0; s < 8; ++s)
        a[s] = *(const f16x8*)(abase + (size_t)(s >> 1) * NH + 32 * (s & 1));
    f32x4 acc[4];
    #pragma unroll
    for (int nt = 0; nt < 4; ++nt) acc[nt] = (f32x4){0.f, 0.f, 0.f, 0.f};
    #pragma unroll
    for (int s = 0; s < 8; ++s)
        #pragma unroll
        for (int nt = 0; nt < 4; ++nt)
            acc[nt] = __builtin_amdgcn_mfma_f32_16x16x32_f16(a[s], b[nt][s], acc[nt], 0, 0, 0);
    float o0[4], o1[4];
    #pragma unroll
    for (int reg = 0; reg < 4; ++reg) { o0[reg] = 0.f; o1[reg] = 0.f; }
    #pragma unroll
    for (int nt = 0; nt < 4; ++nt)
        #pragma unroll
        for (int reg = 0; reg < 4; ++reg) {
            float v = fmaxf(acc[nt][reg] + bm1v[nt], 0.f);
            o0[reg] = fmaf(v, w20[nt], o0[reg]);
            o1[reg] = fmaf(v, w21[nt], o1[reg]);
        }
    #pragma unroll
    for (int reg = 0; reg < 4; ++reg) {
        #pragma unroll
        for (int m = 8; m > 0; m >>= 1) {
            o0[reg] += __shfl_xor(o0[reg], m);
            o1[reg] += __shfl_xor(o1[reg], m);
        }
    }
    if ((lane & 15) == 0) {
        int rbase = row0 + (lane >> 4) * 4;
        #pragma unroll
        for (int reg = 0; reg < 4; ++reg) {
            out[(rbase + reg) * 2 + 0] = o0[reg] + bm20;
            out[(rbase + reg) * 2 + 1] = o1[reg] + bm21;
        }
    }
}

extern "C" void kernel_launch(void* const* d_in, const int* in_sizes, int n_in,
                              void* d_out, int out_size, void* d_ws, size_t ws_size,
                              hipStream_t stream)
{
    const float* feature = (const float*)d_in[0];
    const int*   src     = (const int*)d_in[1];
    const int*   dst     = (const int*)d_in[2];
    const float* W1      = (const float*)d_in[3];
    const float* b1      = (const float*)d_in[4];
    const float* W2      = (const float*)d_in[5];
    const float* b2      = (const float*)d_in[6];
    const float* thetas  = (const float*)d_in[7];
    const float* Wm1     = (const float*)d_in[8];
    const float* bm1     = (const float*)d_in[9];
    const float* Wm2     = (const float*)d_in[10];
    const float* bm2     = (const float*)d_in[11];
    float* out = (float*)d_out;

    const size_t NH = (size_t)N_NODES * H_FEATS;   // 6.4M elems
    const int NPAD = 100352;
    float*  dinv    = (float*)d_ws;                   // N
    int*    rowp    = (int*)(dinv + NPAD);            // N+1
    int*    blkcnt  = rowp + NPAD;                    // 512*500 (1 MB)
    int*    boff    = blkcnt + NBA * NBUK;            // 512*500 (1 MB)
    int*    buktot  = boff + NBA * NBUK;              // 500
    int*    bukbase = buktot + 512;                   // 500
    int*    ebuck   = bukbase + 512;                  // E packed int (6.4 MB)
    int*    esrc    = ebuck + N_EDGES;                // E int (6.4 MB)
    __half* Lh      = (__half*)(esrc + N_EDGES);      // 4 x NH halfs (51.2 MB)
    __half* Bpack   = Lh + 4 * NH;                    // 16384 halfs
    __half* W1p     = Bpack + 16384;                  // 8192 halfs
    __half* W2p     = W1p + 8192;                     // 4096 halfs
    // total ws use ≈ 68 MB; no memsets (every array fully written before read)

    prep_kernel<<<112, 256, 0, stream>>>(thetas, Wm1, W1, W2, Bpack, W1p, W2p);
    trunk_mfma_kernel<<<1563, 256, 0, stream>>>(feature, W1p, b1, W2p, b2, Lh);  // -> L0h

    bucketA_kernel<<<NBA, 256, 0, stream>>>(dst, blkcnt);
    bucketB1_kernel<<<NBUK, 512, 0, stream>>>(blkcnt, boff, buktot);
    bucketB2_kernel<<<1, 512, 0, stream>>>(buktot, bukbase, rowp);
    bucketC_kernel<<<NBA, 256, 0, stream>>>(src, dst, boff, bukbase, ebuck);
    bucketD_kernel<<<NBUK, 256, 0, stream>>>(ebuck, bukbase, buktot, rowp, dinv, esrc);

    for (int k = 1; k <= 3; ++k)
        gather_kernel<<<25000, 256, 0, stream>>>(Lh + (size_t)(k - 1) * NH, rowp, esrc,
                                                 dinv, Lh + (size_t)k * NH);

    final_mfma_kernel<<<1563, 256, 0, stream>>>(Lh, Bpack, Wm2, bm1, bm2, out);
}

// Round 23
// 212.029 us; speedup vs baseline: 1.1235x; 1.1235x over previous
//
#include <hip/hip_runtime.h>
#include <hip/hip_fp16.h>
#include <math.h>

#define N_NODES 100000
#define N_EDGES 1600000
#define IN_FEATS 128
#define H_FEATS 64
#define NBUK 500          // buckets
#define BSZ 200           // nodes per bucket (500*200 = 100000)
#define NBA 512           // blocks for count/scatter
#define ACHUNK 3125       // 512*3125 = 1600000 exactly

typedef _Float16 f16x8 __attribute__((ext_vector_type(8)));
typedef float f32x4 __attribute__((ext_vector_type(4)));

// ---------------- A: per-block bucket histogram (LDS atomics only) ----------------
__global__ __launch_bounds__(256) void bucketA_kernel(const int* __restrict__ dst,
                                                      int* __restrict__ blkcnt) {
    __shared__ int cnt[NBUK];
    int t = threadIdx.x;
    for (int i = t; i < NBUK; i += 256) cnt[i] = 0;
    __syncthreads();
    int e0 = blockIdx.x * ACHUNK;
    for (int e = e0 + t; e < e0 + ACHUNK; e += 256)
        atomicAdd(&cnt[dst[e] / BSZ], 1);
    __syncthreads();
    for (int i = t; i < NBUK; i += 256)
        blkcnt[blockIdx.x * NBUK + i] = cnt[i];   // coalesced
}

// ---------------- B1: per-bucket exclusive scan over blocks + totals ----------------
__global__ __launch_bounds__(512) void bucketB1_kernel(const int* __restrict__ blkcnt,
                                                       int* __restrict__ boff,
                                                       int* __restrict__ buktot) {
    __shared__ int tmp[512];
    int b = blockIdx.x;      // bucket
    int t = threadIdx.x;     // block index
    int v = blkcnt[t * NBUK + b];
    tmp[t] = v;
    __syncthreads();
    #pragma unroll
    for (int off = 1; off < 512; off <<= 1) {
        int x = (t >= off) ? tmp[t - off] : 0;
        __syncthreads();
        tmp[t] += x;
        __syncthreads();
    }
    boff[t * NBUK + b] = tmp[t] - v;
    if (t == 511) buktot[b] = tmp[511];
}

// ---------------- B2: exclusive scan of bucket totals ----------------
__global__ __launch_bounds__(512) void bucketB2_kernel(const int* __restrict__ buktot,
                                                       int* __restrict__ bukbase,
                                                       int* __restrict__ rowp) {
    __shared__ int tmp[512];
    int t = threadIdx.x;
    int v = (t < NBUK) ? buktot[t] : 0;
    tmp[t] = v;
    __syncthreads();
    #pragma unroll
    for (int off = 1; off < 512; off <<= 1) {
        int x = (t >= off) ? tmp[t - off] : 0;
        __syncthreads();
        tmp[t] += x;
        __syncthreads();
    }
    if (t < NBUK) bukbase[t] = tmp[t] - v;
    if (t == 0) rowp[N_NODES] = N_EDGES;
}

// ---------------- C: scatter packed edges into bucket-sorted ebuck ----------------
// pack = (src << 8) | (dst % BSZ): src < 2^17, local dst < 2^8 -> 25 bits.
__global__ __launch_bounds__(256) void bucketC_kernel(const int* __restrict__ src,
                                                      const int* __restrict__ dst,
                                                      const int* __restrict__ boff,
                                                      const int* __restrict__ bukbase,
                                                      int* __restrict__ ebuck) {
    __shared__ int sbase[NBUK];
    __shared__ int cur[NBUK];
    int t = threadIdx.x;
    for (int i = t; i < NBUK; i += 256) {
        sbase[i] = bukbase[i] + boff[blockIdx.x * NBUK + i];
        cur[i] = 0;
    }
    __syncthreads();
    int e0 = blockIdx.x * ACHUNK;
    for (int e = e0 + t; e < e0 + ACHUNK; e += 256) {
        int d = dst[e];
        int b = d / BSZ;
        int r = atomicAdd(&cur[b], 1);
        ebuck[sbase[b] + r] = (src[e] << 8) | (d - b * BSZ);
    }
}

// ---------------- D1: per-bucket degrees -> rowp (global slot base) + dinv ----------
__global__ __launch_bounds__(256) void bucketD1_kernel(const int* __restrict__ ebuck,
                                                       const int* __restrict__ bukbase,
                                                       const int* __restrict__ buktot,
                                                       int* __restrict__ rowp,
                                                       float* __restrict__ dinv) {
    __shared__ int deg[BSZ];
    __shared__ int tmp[256];
    int t = threadIdx.x;
    int buk = blockIdx.x;
    int nlo = buk * BSZ;
    int base = bukbase[buk];
    int cnt = buktot[buk];
    for (int i = t; i < BSZ; i += 256) deg[i] = 0;
    __syncthreads();
    for (int k = t; k < cnt; k += 256)
        atomicAdd(&deg[ebuck[base + k] & 255], 1);
    __syncthreads();
    int v = (t < BSZ) ? deg[t] : 0;
    tmp[t] = v;
    __syncthreads();
    #pragma unroll
    for (int off = 1; off < 256; off <<= 1) {
        int x = (t >= off) ? tmp[t - off] : 0;
        __syncthreads();
        tmp[t] += x;
        __syncthreads();
    }
    if (t < BSZ) {
        rowp[nlo + t] = base + tmp[t] - v;
        dinv[nlo + t] = rsqrtf(fmaxf((float)v, 1.0f));
    }
}

// ---------------- D2: rank packed ebuck (L2/L3-hot) -> epack (src, bits(dinv[src]))
__global__ __launch_bounds__(256) void bucketD2_kernel(const int* __restrict__ ebuck,
                                                       const int* __restrict__ bukbase,
                                                       const int* __restrict__ buktot,
                                                       const int* __restrict__ rowp,
                                                       const float* __restrict__ dinv,
                                                       int2* __restrict__ epack) {
    __shared__ int rp[BSZ];
    __shared__ int cur2[BSZ];
    int t = threadIdx.x;
    int buk = blockIdx.x;
    int nlo = buk * BSZ;
    int base = bukbase[buk];
    int cnt = buktot[buk];
    for (int i = t; i < BSZ; i += 256) { rp[i] = rowp[nlo + i]; cur2[i] = 0; }
    __syncthreads();
    for (int k = t; k < cnt; k += 256) {
        int p = ebuck[base + k];
        int ld = p & 255;
        int s = p >> 8;
        int r = atomicAdd(&cur2[ld], 1);
        epack[rp[ld] + r] = make_int2(s, __float_as_int(dinv[s]));
    }
}

// ---------------- prep: pack Weff/W1/W2 into fp16 MFMA B-fragment order ----------------
// Fragment (s,nt): lane l, elem j holds B[k = 32s + (l>>4)*8 + j][n = nt*16 + (l&15)]
__global__ __launch_bounds__(256) void prep_kernel(const float* __restrict__ thetas,
                                                   const float* __restrict__ Wm1,
                                                   const float* __restrict__ W1,
                                                   const float* __restrict__ W2,
                                                   __half* __restrict__ Bpack,
                                                   __half* __restrict__ W1p,
                                                   __half* __restrict__ W2p) {
    int u = blockIdx.x * 256 + threadIdx.x;
    if (u < 16384) {
        int j = u & 7, lane = (u >> 3) & 63, frag = u >> 9;
        int nt = frag & 3, s = frag >> 2;
        int k = 32 * s + ((lane >> 4) << 3) + j;
        int q = k >> 6, f = k & 63;
        int n = nt * 16 + (lane & 15);
        float acc = 0.f;
        #pragma unroll
        for (int c = 0; c < 3; ++c)
            acc = fmaf(thetas[c * 4 + q], Wm1[(c * 64 + f) * 64 + n], acc);
        Bpack[u] = __float2half(acc);
    } else if (u < 16384 + 8192) {
        int v = u - 16384;
        int j = v & 7, lane = (v >> 3) & 63, frag = v >> 9;   // frag 0..15
        int nt = frag & 3, s = frag >> 2;
        int k = 32 * s + ((lane >> 4) << 3) + j;              // 0..127
        int n = nt * 16 + (lane & 15);
        W1p[v] = __float2half(W1[k * 64 + n]);
    } else if (u < 16384 + 8192 + 4096) {
        int v = u - 24576;
        int j = v & 7, lane = (v >> 3) & 63, frag = v >> 9;   // frag 0..7
        int nt = frag & 3, s2 = frag >> 2;
        int k = 32 * s2 + ((lane >> 4) << 3) + j;             // 0..63
        int n = nt * 16 + (lane & 15);
        W2p[v] = __float2half(W2[k * 64 + n]);
    }
}

// ---------------- trunk (MFMA): H = fp16(relu(relu(X@W1+b1)@W2+b2)) ----------------
// ONE 16-row tile per wave. Layouts identical to final_mfma (verified).
// Swizzle: byte ^= (row&7)<<4.
__global__ __launch_bounds__(256) void trunk_mfma_kernel(
    const float* __restrict__ X, const __half* __restrict__ W1p, const float* __restrict__ b1,
    const __half* __restrict__ W2p, const float* __restrict__ b2, __half* __restrict__ H)
{
    __shared__ __half hl[4][1024];   // 2 KB per wave
    int t = threadIdx.x;
    int wv = t >> 6, lane = t & 63;
    int r_lo = lane & 15;            // A-frag row / D col
    int g = lane >> 4;               // k-group / D row group
    char* myl = (char*)hl[wv];

    int tile = blockIdx.x * 4 + wv;
    if (tile >= 6250) return;        // 6250*16 = 100000 exactly; no barriers below

    const f16x8* w1f = (const f16x8*)W1p;
    const f16x8* w2f = (const f16x8*)W2p;
    f16x8 w1b[16], w2b[8];
    #pragma unroll
    for (int f = 0; f < 16; ++f) w1b[f] = w1f[f * 64 + lane];
    #pragma unroll
    for (int f = 0; f < 8; ++f)  w2b[f] = w2f[f * 64 + lane];
    float b1v[4], b2v[4];
    #pragma unroll
    for (int nt = 0; nt < 4; ++nt) {
        b1v[nt] = b1[nt * 16 + r_lo];
        b2v[nt] = b2[nt * 16 + r_lo];
    }

    int row0 = tile * 16;
    const float* xb = X + (size_t)(row0 + r_lo) * IN_FEATS + g * 8;
    f16x8 a1[4];
    #pragma unroll
    for (int s = 0; s < 4; ++s) {
        float4 f0 = *(const float4*)(xb + 32 * s);
        float4 f1 = *(const float4*)(xb + 32 * s + 4);
        f16x8 a;
        a[0] = (_Float16)f0.x; a[1] = (_Float16)f0.y;
        a[2] = (_Float16)f0.z; a[3] = (_Float16)f0.w;
        a[4] = (_Float16)f1.x; a[5] = (_Float16)f1.y;
        a[6] = (_Float16)f1.z; a[7] = (_Float16)f1.w;
        a1[s] = a;
    }
    f32x4 acc1[4];
    #pragma unroll
    for (int nt = 0; nt < 4; ++nt) acc1[nt] = (f32x4){0.f, 0.f, 0.f, 0.f};
    #pragma unroll
    for (int s = 0; s < 4; ++s)
        #pragma unroll
        for (int nt = 0; nt < 4; ++nt)
            acc1[nt] = __builtin_amdgcn_mfma_f32_16x16x32_f16(a1[s], w1b[s * 4 + nt], acc1[nt], 0, 0, 0);
    #pragma unroll
    for (int nt = 0; nt < 4; ++nt)
        #pragma unroll
        for (int reg = 0; reg < 4; ++reg) {
            int r = g * 4 + reg;
            int c = nt * 16 + r_lo;
            int byte = (r * 128 + c * 2) ^ ((r & 7) << 4);
            *(__half*)(myl + byte) = __float2half(fmaxf(acc1[nt][reg] + b1v[nt], 0.f));
        }
    f16x8 a2[2];
    #pragma unroll
    for (int s2 = 0; s2 < 2; ++s2) {
        int byte = (r_lo * 128 + 64 * s2 + g * 16) ^ ((r_lo & 7) << 4);
        a2[s2] = *(const f16x8*)(myl + byte);
    }
    f32x4 acc2[4];
    #pragma unroll
    for (int nt = 0; nt < 4; ++nt) acc2[nt] = (f32x4){0.f, 0.f, 0.f, 0.f};
    #pragma unroll
    for (int s2 = 0; s2 < 2; ++s2)
        #pragma unroll
        for (int nt = 0; nt < 4; ++nt)
            acc2[nt] = __builtin_amdgcn_mfma_f32_16x16x32_f16(a2[s2], w2b[s2 * 4 + nt], acc2[nt], 0, 0, 0);
    #pragma unroll
    for (int nt = 0; nt < 4; ++nt)
        #pragma unroll
        for (int reg = 0; reg < 4; ++reg) {
            int r = g * 4 + reg;
            int c = nt * 16 + r_lo;
            int byte = (r * 128 + c * 2) ^ ((r & 7) << 4);
            *(__half*)(myl + byte) = __float2half(fmaxf(acc2[nt][reg] + b2v[nt], 0.f));
        }
    #pragma unroll
    for (int h2 = 0; h2 < 2; ++h2) {
        int R = (lane >> 3) + 8 * h2;    // row 0..15
        int w = lane & 7;                // 16B slot
        int byte = (R * 128 + 16 * (w ^ (R & 7)));
        f16x8 hv = *(const f16x8*)(myl + byte);
        *(f16x8*)(H + (size_t)(row0 + R) * 64 + w * 8) = hv;
    }
}

// ---------------- gather pass: Fnew[n] = Fprev[n] - dinv[n]*sum_e w_e*Fprev[s_e]
// half tables (128B row per edge), fp32 accumulate; one wave per node.
// Unroll ladder 16/8/4/1: up to 16 row-loads in flight per wave; weight rides
// in the same 8B epack record as the index (no dependent second load).
__global__ __launch_bounds__(256) void gather_kernel(
    const __half* __restrict__ Fprev, const int* __restrict__ rowp,
    const int2* __restrict__ epack, const float* __restrict__ dinv,
    __half* __restrict__ Fnew)
{
    int wv = __builtin_amdgcn_readfirstlane(threadIdx.x >> 6);
    int wid = blockIdx.x * 4 + wv;   // node id (uniform)
    int lane = threadIdx.x & 63;
    int beg = rowp[wid], end = rowp[wid + 1];
    float acc = 0.0f;
    int j = beg;
    for (; j + 15 < end; j += 16) {
        int2 e[16];
        #pragma unroll
        for (int q = 0; q < 16; ++q) e[q] = epack[j + q];
        float v[16];
        #pragma unroll
        for (int q = 0; q < 16; ++q)
            v[q] = __half2float(Fprev[(size_t)e[q].x * 64 + lane]);
        #pragma unroll
        for (int q = 0; q < 16; ++q)
            acc = fmaf(v[q], __int_as_float(e[q].y), acc);
    }
    for (; j + 7 < end; j += 8) {
        int2 e[8];
        #pragma unroll
        for (int q = 0; q < 8; ++q) e[q] = epack[j + q];
        float v[8];
        #pragma unroll
        for (int q = 0; q < 8; ++q)
            v[q] = __half2float(Fprev[(size_t)e[q].x * 64 + lane]);
        #pragma unroll
        for (int q = 0; q < 8; ++q)
            acc = fmaf(v[q], __int_as_float(e[q].y), acc);
    }
    for (; j + 3 < end; j += 4) {
        int2 e[4];
        #pragma unroll
        for (int q = 0; q < 4; ++q) e[q] = epack[j + q];
        float v[4];
        #pragma unroll
        for (int q = 0; q < 4; ++q)
            v[q] = __half2float(Fprev[(size_t)e[q].x * 64 + lane]);
        #pragma unroll
        for (int q = 0; q < 4; ++q)
            acc = fmaf(v[q], __int_as_float(e[q].y), acc);
    }
    for (; j < end; ++j) {
        int2 e = epack[j];
        acc = fmaf(__half2float(Fprev[(size_t)e.x * 64 + lane]), __int_as_float(e.y), acc);
    }
    float self = __half2float(Fprev[(size_t)wid * 64 + lane]);
    Fnew[(size_t)wid * 64 + lane] = __float2half(self - acc * dinv[wid]);
}

// ---------------- final (MFMA): out = relu(A@B + bm1) @ Wm2 + bm2 ----------------
// ONE 16-row tile per wave. A = [L0|L1|L2|L3] fp16 contiguous; B pre-packed
// fragment order. D: col n = nt*16 + (l&15), row = (l>>4)*4 + reg.
__global__ __launch_bounds__(256) void final_mfma_kernel(
    const __half* __restrict__ L0h, const __half* __restrict__ Bpack,
    const float* __restrict__ Wm2, const float* __restrict__ bm1,
    const float* __restrict__ bm2, float* __restrict__ out)
{
    const size_t NH = (size_t)N_NODES * 64;
    int t = threadIdx.x;
    int wv = t >> 6;
    int lane = t & 63;
    int tile = blockIdx.x * 4 + wv;
    if (tile >= 6250) return;          // 6250 * 16 = 100000 exactly

    const f16x8* bp = (const f16x8*)Bpack;
    f16x8 b[4][8];
    #pragma unroll
    for (int s = 0; s < 8; ++s)
        #pragma unroll
        for (int nt = 0; nt < 4; ++nt)
            b[nt][s] = bp[(s * 4 + nt) * 64 + lane];

    float bm1v[4], w20[4], w21[4];
    #pragma unroll
    for (int nt = 0; nt < 4; ++nt) {
        int n = nt * 16 + (lane & 15);
        bm1v[nt] = bm1[n];
        w20[nt] = Wm2[n * 2 + 0];
        w21[nt] = Wm2[n * 2 + 1];
    }
    float bm20 = bm2[0], bm21 = bm2[1];

    int row0 = tile * 16;
    const __half* abase = L0h + (size_t)(row0 + (lane & 15)) * 64 + ((lane >> 4) << 3);
    f16x8 a[8];
    #pragma unroll
    for (int s = 0; s < 8; ++s)
        a[s] = *(const f16x8*)(abase + (size_t)(s >> 1) * NH + 32 * (s & 1));
    f32x4 acc[4];
    #pragma unroll
    for (int nt = 0; nt < 4; ++nt) acc[nt] = (f32x4){0.f, 0.f, 0.f, 0.f};
    #pragma unroll
    for (int s = 0; s < 8; ++s)
        #pragma unroll
        for (int nt = 0; nt < 4; ++nt)
            acc[nt] = __builtin_amdgcn_mfma_f32_16x16x32_f16(a[s], b[nt][s], acc[nt], 0, 0, 0);
    float o0[4], o1[4];
    #pragma unroll
    for (int reg = 0; reg < 4; ++reg) { o0[reg] = 0.f; o1[reg] = 0.f; }
    #pragma unroll
    for (int nt = 0; nt < 4; ++nt)
        #pragma unroll
        for (int reg = 0; reg < 4; ++reg) {
            float v = fmaxf(acc[nt][reg] + bm1v[nt], 0.f);
            o0[reg] = fmaf(v, w20[nt], o0[reg]);
            o1[reg] = fmaf(v, w21[nt], o1[reg]);
        }
    #pragma unroll
    for (int reg = 0; reg < 4; ++reg) {
        #pragma unroll
        for (int m = 8; m > 0; m >>= 1) {
            o0[reg] += __shfl_xor(o0[reg], m);
            o1[reg] += __shfl_xor(o1[reg], m);
        }
    }
    if ((lane & 15) == 0) {
        int rbase = row0 + (lane >> 4) * 4;
        #pragma unroll
        for (int reg = 0; reg < 4; ++reg) {
            out[(rbase + reg) * 2 + 0] = o0[reg] + bm20;
            out[(rbase + reg) * 2 + 1] = o1[reg] + bm21;
        }
    }
}

extern "C" void kernel_launch(void* const* d_in, const int* in_sizes, int n_in,
                              void* d_out, int out_size, void* d_ws, size_t ws_size,
                              hipStream_t stream)
{
    const float* feature = (const float*)d_in[0];
    const int*   src     = (const int*)d_in[1];
    const int*   dst     = (const int*)d_in[2];
    const float* W1      = (const float*)d_in[3];
    const float* b1      = (const float*)d_in[4];
    const float* W2      = (const float*)d_in[5];
    const float* b2      = (const float*)d_in[6];
    const float* thetas  = (const float*)d_in[7];
    const float* Wm1     = (const float*)d_in[8];
    const float* bm1     = (const float*)d_in[9];
    const float* Wm2     = (const float*)d_in[10];
    const float* bm2     = (const float*)d_in[11];
    float* out = (float*)d_out;

    const size_t NH = (size_t)N_NODES * H_FEATS;   // 6.4M elems
    const int NPAD = 100352;
    float*  dinv    = (float*)d_ws;                   // N
    int*    rowp    = (int*)(dinv + NPAD);            // N+1
    int*    blkcnt  = rowp + NPAD;                    // 512*500 (1 MB)
    int*    boff    = blkcnt + NBA * NBUK;            // 512*500 (1 MB)
    int*    buktot  = boff + NBA * NBUK;              // 500
    int*    bukbase = buktot + 512;                   // 500
    int*    ebuck   = bukbase + 512;                  // E packed int (6.4 MB)
    int2*   epack   = (int2*)(ebuck + N_EDGES);       // E int2 (12.8 MB)
    __half* Lh      = (__half*)(epack + N_EDGES);     // 4 x NH halfs (51.2 MB)
    __half* Bpack   = Lh + 4 * NH;                    // 16384 halfs
    __half* W1p     = Bpack + 16384;                  // 8192 halfs
    __half* W2p     = W1p + 8192;                     // 4096 halfs
    // total ws use ≈ 74 MB; no memsets (every array fully written before read)

    prep_kernel<<<112, 256, 0, stream>>>(thetas, Wm1, W1, W2, Bpack, W1p, W2p);
    trunk_mfma_kernel<<<1563, 256, 0, stream>>>(feature, W1p, b1, W2p, b2, Lh);  // -> L0h

    bucketA_kernel<<<NBA, 256, 0, stream>>>(dst, blkcnt);
    bucketB1_kernel<<<NBUK, 512, 0, stream>>>(blkcnt, boff, buktot);
    bucketB2_kernel<<<1, 512, 0, stream>>>(buktot, bukbase, rowp);
    bucketC_kernel<<<NBA, 256, 0, stream>>>(src, dst, boff, bukbase, ebuck);
    bucketD1_kernel<<<NBUK, 256, 0, stream>>>(ebuck, bukbase, buktot, rowp, dinv);
    bucketD2_kernel<<<NBUK, 256, 0, stream>>>(ebuck, bukbase, buktot, rowp, dinv, epack);

    for (int k = 1; k <= 3; ++k)
        gather_kernel<<<25000, 256, 0, stream>>>(Lh + (size_t)(k - 1) * NH, rowp, epack,
                                                 dinv, Lh + (size_t)k * NH);

    final_mfma_kernel<<<1563, 256, 0, stream>>>(Lh, Bpack, Wm2, bm1, bm2, out);
}